// Round 6
// baseline (1671.884 us; speedup 1.0000x reference)
//
#include <hip/hip_runtime.h>

typedef __attribute__((ext_vector_type(8))) short bf16x8;
typedef __attribute__((ext_vector_type(4))) float f32x4;
typedef unsigned short u16;

#define MFMA(a,b,c) __builtin_amdgcn_mfma_f32_16x16x32_bf16((a),(b),(c),0,0,0)

__device__ __forceinline__ short f2bf(float f){
  union { float f; unsigned u; } v; v.f = f;
  unsigned r = v.u + 0x7FFFu + ((v.u >> 16) & 1u);
  return (short)(r >> 16);
}
__device__ __forceinline__ float bf2f(short s){
  union { unsigned u; float f; } v; v.u = ((unsigned)(unsigned short)s) << 16; return v.f;
}
__device__ __forceinline__ bf16x8 pack8(f32x4 x, f32x4 y){
  bf16x8 r;
  r[0]=f2bf(x[0]); r[1]=f2bf(x[1]); r[2]=f2bf(x[2]); r[3]=f2bf(x[3]);
  r[4]=f2bf(y[0]); r[5]=f2bf(y[1]); r[6]=f2bf(y[2]); r[7]=f2bf(y[3]);
  return r;
}
// XOR-swizzled LDS addressing (16B-chunk granularity)
__device__ __forceinline__ int swz(int row, int col, int rowShorts){
  int byte = col << 1;
  int chunk = (byte & ~15) ^ ((row & 7) << 4);
  return row * rowShorts + ((chunk | (byte & 15)) >> 1);
}
// async global->LDS, 16B per lane; lds ptr = wave-uniform base (HW adds lane*16)
__device__ __forceinline__ void gload16(void* lp, const void* gp){
  __builtin_amdgcn_global_load_lds((const __attribute__((address_space(1))) unsigned*)gp,
                                   (__attribute__((address_space(3))) unsigned*)lp, 16, 0, 0);
}
// stage 32KB (128x128 bf16, pre-swizzled image) into LDS (512 threads)
__device__ __forceinline__ void stageW(short* buf, const short* img, int w, int lane){
  const char* gp = (const char*)img;
  char* lp = (char*)buf;
  #pragma unroll
  for (int r=0; r<4; ++r)
    gload16(lp + r*8192 + w*1024, gp + r*8192 + w*1024 + lane*16);
}
// stage 24KB (96x128 bf16) image block
__device__ __forceinline__ void stageQ(short* buf, const short* img, int w, int lane){
  const char* gp = (const char*)img;
  char* lp = (char*)buf;
  #pragma unroll
  for (int r=0; r<3; ++r)
    gload16(lp + r*8192 + w*1024, gp + r*8192 + w*1024 + lane*16);
}
// stage [128 rows][128 cols] bf16 from d_out row-scratch (row stride 1536 shorts),
// swizzle applied at the per-lane SOURCE address; LDS dest linear. holeoff 0=ctxo, 768=ctx.
__device__ __forceinline__ void stageCtx(short* buf, const u16* rowb, int kb2, int holeoff, int w, int lane){
  int tid = w*64 + lane;
  #pragma unroll
  for (int i=0;i<4;++i){
    int id = i*512 + tid;
    int row = id>>4, sc = id&15;
    int kc = sc ^ (row&7);
    gload16((char*)buf + i*8192 + w*1024,
            rowb + (size_t)row*1536 + holeoff + kb2*128 + kc*8);
  }
}

// ---------------- prep kernels ----------------
__global__ void prep_w(const float* __restrict__ Wq, const float* __restrict__ Wo,
                       const float* __restrict__ Wg1, short* __restrict__ WqI,
                       short* __restrict__ WoI, short* __restrict__ WaI, short* __restrict__ WbI){
  __shared__ short lt[128][136];
  int blk = blockIdx.x;            // 144 = 4 mats * 6 ktiles * 6 jtiles
  int mat = blk / 36, t = blk % 36, kt = t / 6, jt = t % 6;
  const float* src = (mat==0)? Wq : (mat==1)? Wo : (mat==2)? Wg1 : (Wg1 + (size_t)768*768);
  int tid = threadIdx.x;           // 256
  for (int it=0; it<64; ++it){
    int idx = it*256 + tid;
    int kl = idx >> 7, jl = idx & 127;
    lt[jl][kl] = f2bf(src[(size_t)(kt*128+kl)*768 + jt*128 + jl]);
  }
  __syncthreads();
  for (int cc=0; cc<8; ++cc){
    int ci = cc*256 + tid;
    int jl = ci >> 4, sc = ci & 15;
    int jg = jt*128 + jl;
    short* dst; size_t base; int row;
    if (mat==0){ int bh = jg / 96; row = jg % 96; dst = WqI; base = (size_t)(bh*6 + kt)*12288; }
    else { row = jl; dst = (mat==1)?WoI:(mat==2)?WaI:WbI; base = (size_t)(jt*6 + kt)*16384; }
    int kkb = ((sc ^ (row & 7)) << 3);
    bf16x8 v = *(const bf16x8*)&lt[jl][kkb];
    *(bf16x8*)&dst[base + (size_t)row*128 + sc*8] = v;
  }
}

__global__ void prep_kv(const float* __restrict__ ce, const float* __restrict__ Wk,
                        const float* __restrict__ bk, const float* __restrict__ Wv,
                        const float* __restrict__ bv, short* __restrict__ Kc, short* __restrict__ VT){
  __shared__ float sh[8][768];
  int c0 = blockIdx.x*8, j = threadIdx.x;   // 8 blocks x 768 threads
  #pragma unroll
  for (int c2=0; c2<8; ++c2) sh[c2][j] = ce[(size_t)(c0+c2)*768 + j];
  __syncthreads();
  float aK[8], aV[8];
  float bkj = bk[j], bvj = bv[j];
  #pragma unroll
  for (int c2=0; c2<8; ++c2){ aK[c2]=bkj; aV[c2]=bvj; }
  for (int h=0; h<768; ++h){
    float wk = Wk[(size_t)h*768+j], wv = Wv[(size_t)h*768+j];
    #pragma unroll
    for (int c2=0; c2<8; ++c2){ float x = sh[c2][h]; aK[c2] += x*wk; aV[c2] += x*wv; }
  }
  #pragma unroll
  for (int c2=0; c2<8; ++c2){
    Kc[(size_t)(c0+c2)*768 + j] = f2bf(aK[c2]);
    VT[(size_t)j*64 + c0+c2] = f2bf(aV[c2]);
  }
}

__global__ void prep_misc(const float* __restrict__ Wg1, const float* __restrict__ ce,
                          float* __restrict__ wg1c, float* __restrict__ cp){
  int i = blockIdx.x*256 + threadIdx.x;   // 0..1535
  if (blockIdx.x < 3){
    int j = i; float s = 0.f;
    for (int r=0; r<768; ++r) s += Wg1[(size_t)(1536+r)*768 + j];
    wg1c[j] = s;
  } else {
    int h = i - 768; float s = 0.f;
    for (int c2=0; c2<64; ++c2) s += ce[(size_t)c2*768 + h];
    cp[h] = s * (1.f/64.f);
  }
}

__global__ void pool1(const float* __restrict__ hs, float* __restrict__ tpp){
  int b = blockIdx.x >> 5, sc = blockIdx.x & 31;
  size_t base = ((size_t)b*4096 + (size_t)sc*128)*768;
  for (int h = threadIdx.x; h < 768; h += 256){
    float s = 0.f;
    #pragma unroll 4
    for (int s2=0; s2<128; ++s2) s += __builtin_nontemporal_load(&hs[base + (size_t)s2*768 + h]);
    tpp[(size_t)blockIdx.x*768 + h] = s;
  }
}
__global__ void pool2(const float* __restrict__ tpp, float* __restrict__ tp){
  int b = blockIdx.x / 3, hc = blockIdx.x % 3;
  int h = hc*256 + threadIdx.x;
  float s = 0.f;
  for (int k=0; k<32; ++k) s += tpp[((size_t)b*32 + k)*768 + h];
  tp[(size_t)b*768 + h] = s * (1.f/4096.f);
}
__global__ void pool3(const float* __restrict__ tp, const float* __restrict__ cp, float* __restrict__ rel){
  int b = blockIdx.x;
  float a=0.f, n1=0.f, n2=0.f;
  for (int h = threadIdx.x; h < 768; h += 256){
    float t = tp[(size_t)b*768 + h], c = cp[h];
    a += t*c; n1 += t*t; n2 += c*c;
  }
  #pragma unroll
  for (int m=1; m<64; m<<=1){ a+=__shfl_xor(a,m); n1+=__shfl_xor(n1,m); n2+=__shfl_xor(n2,m); }
  __shared__ float r3[3][4];
  int w = threadIdx.x >> 6;
  if ((threadIdx.x & 63) == 0){ r3[0][w]=a; r3[1][w]=n1; r3[2][w]=n2; }
  __syncthreads();
  if (threadIdx.x == 0){
    float A = r3[0][0]+r3[0][1]+r3[0][2]+r3[0][3];
    float N1= r3[1][0]+r3[1][1]+r3[1][2]+r3[1][3];
    float N2= r3[2][0]+r3[2][1]+r3[2][2]+r3[2][3];
    rel[b] = A / (fmaxf(sqrtf(N1),1e-8f) * fmaxf(sqrtf(N2),1e-8f));
  }
}

// ---------------- FUSED: Q-proj + attn + Wo + gate MLP + residual + LayerNorm ----------------
// Only persistent register array: af[24] (hs bf16, const-indexed). ctx -> hole2, ctxo -> hole1.
__global__ void __launch_bounds__(512, 2) fused(
    const float* __restrict__ hs, const short* __restrict__ WqI,
    const short* __restrict__ WoI, const short* __restrict__ WaI,
    const short* __restrict__ WbI, const short* __restrict__ Kc,
    const short* __restrict__ VT, const float* __restrict__ bq,
    const float* __restrict__ bo, const float* __restrict__ bg1,
    const float* __restrict__ wg1c, const float* __restrict__ Wg2,
    const float* __restrict__ bg2, const float* __restrict__ rel,
    const float* __restrict__ lng, const float* __restrict__ lnb,
    float* __restrict__ outp){
  extern __shared__ char lds[];
  short* wst0 = (short*)lds;                 // B dbuf
  short* wst1 = (short*)(lds + 32768);
  short* ast0 = (short*)(lds + 65536);       // A dbuf (Wo/gateB); attention overlay: qh
  short* ast1 = (short*)(lds + 98304);       //                    attention overlay: attb
  short* qh   = ast0;
  short* attb = ast1;
  float* aavgL= (float*)(lds + 114688);      // 32KB; reused as gl after attn_avg stores
  float* gl   = (float*)(lds + 114688);
  const int tid = threadIdx.x, lane = tid & 63, w = tid >> 6;
  const int l15 = lane & 15, g = lane >> 4;
  const size_t t0 = (size_t)blockIdx.x * 128;
  const int arow = w*16 + l15;
  const int drow = w*16 + g*4;
  const float relb = rel[t0 >> 12];
  u16* myW = (u16*)outp + t0*1536;           // [0,768)=ctxo bf16, [768,1536)=ctx bf16

  stageQ(wst0, WqI, w, lane);

  bf16x8 af[24];
  #pragma unroll
  for (int kk=0; kk<24; ++kk){
    const float* p = hs + (t0+arow)*768 + kk*32 + g*8;
    f32x4 x = __builtin_nontemporal_load((const f32x4*)p);
    f32x4 y = __builtin_nontemporal_load((const f32x4*)(p+4));
    af[kk] = pack8(x, y);
  }
  for (int i=tid; i<8192; i+=512) aavgL[i] = 0.f;
  __syncthreads();

  // ======== phase 1: per-head Q-GEMM + attention, ctx -> hole2 ========
  #pragma unroll 1
  for (int h=0; h<8; ++h){
    f32x4 qa[6];
    #pragma unroll
    for (int i=0;i<6;++i) qa[i]=(f32x4){0.f,0.f,0.f,0.f};
    #pragma unroll
    for (int kb2=0; kb2<6; ++kb2){
      short* bc = (kb2&1)? wst1 : wst0;
      short* bn = (kb2&1)? wst0 : wst1;
      if (kb2<5)      stageQ(bn, WqI + (size_t)(h*6+kb2+1)*12288, w, lane);
      else if (h<7)   stageQ(bn, WqI + (size_t)((h+1)*6)*12288, w, lane);
      else            stageW(bn, WoI, w, lane);
      #pragma unroll
      for (int ks=0; ks<4; ++ks){
        bf16x8 a = af[kb2*4+ks];
        #pragma unroll
        for (int nt=0; nt<6; ++nt)
          qa[nt] = MFMA(a, *(const bf16x8*)&bc[swz(nt*16+l15, ks*32+g*8, 128)], qa[nt]);
      }
      __syncthreads();
    }
    // Q epilogue -> qh (wave-local rows)
    #pragma unroll
    for (int nt=0; nt<6; ++nt)
      #pragma unroll
      for (int r=0; r<4; ++r)
        qh[swz(drow+r, nt*16+l15, 128)] = f2bf((qa[nt][r] + bq[h*96+nt*16+l15]) * 0.10206207262f);
    // scores + softmax (wave-local)
    {
      f32x4 sa[4];
      #pragma unroll
      for (int i=0;i<4;++i) sa[i]=(f32x4){0.f,0.f,0.f,0.f};
      #pragma unroll
      for (int ks=0; ks<3; ++ks){
        bf16x8 a = *(const bf16x8*)&qh[swz(arow, ks*32+g*8, 128)];
        #pragma unroll
        for (int cf2=0; cf2<4; ++cf2)
          sa[cf2] = MFMA(a, *(const bf16x8*)&Kc[(size_t)(cf2*16+l15)*768 + h*96 + ks*32 + g*8], sa[cf2]);
      }
      #pragma unroll
      for (int r=0; r<4; ++r){
        float v0=sa[0][r], v1=sa[1][r], v2=sa[2][r], v3=sa[3][r];
        float m = fmaxf(fmaxf(v0,v1),fmaxf(v2,v3));
        m = fmaxf(m,__shfl_xor(m,1)); m = fmaxf(m,__shfl_xor(m,2));
        m = fmaxf(m,__shfl_xor(m,4)); m = fmaxf(m,__shfl_xor(m,8));
        float e0=__expf(v0-m),e1=__expf(v1-m),e2=__expf(v2-m),e3=__expf(v3-m);
        float s=e0+e1+e2+e3;
        s+=__shfl_xor(s,1); s+=__shfl_xor(s,2); s+=__shfl_xor(s,4); s+=__shfl_xor(s,8);
        float inv = 1.f/s;
        e0*=inv; e1*=inv; e2*=inv; e3*=inv;
        attb[swz(drow+r,  0+l15, 64)] = f2bf(e0);
        attb[swz(drow+r, 16+l15, 64)] = f2bf(e1);
        attb[swz(drow+r, 32+l15, 64)] = f2bf(e2);
        attb[swz(drow+r, 48+l15, 64)] = f2bf(e3);
        float* ap = &aavgL[(drow+r)*64 + l15];
        ap[0]  += e0*0.125f; ap[16] += e1*0.125f;
        ap[32] += e2*0.125f; ap[48] += e3*0.125f;
      }
    }
    // PV -> ctx bf16 -> hole2
    {
      f32x4 pv[6];
      #pragma unroll
      for (int i=0;i<6;++i) pv[i]=(f32x4){0.f,0.f,0.f,0.f};
      #pragma unroll
      for (int ks=0; ks<2; ++ks){
        bf16x8 a = *(const bf16x8*)&attb[swz(arow, ks*32+g*8, 64)];
        #pragma unroll
        for (int nt=0; nt<6; ++nt)
          pv[nt] = MFMA(a, *(const bf16x8*)&VT[(size_t)(h*96 + nt*16 + l15)*64 + ks*32 + g*8], pv[nt]);
      }
      #pragma unroll
      for (int nt=0; nt<6; ++nt)
        #pragma unroll
        for (int r=0; r<4; ++r)
          myW[(size_t)(drow+r)*1536 + 768 + h*96 + nt*16 + l15] = (u16)f2bf(pv[nt][r]);
    }
  }
  __syncthreads();   // drains ctx stores (vmcnt0 before barrier) + frees qh/attb overlays
  // attn_avg out
  #pragma unroll
  for (int cf2=0; cf2<4; ++cf2)
    #pragma unroll
    for (int r=0; r<4; ++r)
      __builtin_nontemporal_store(aavgL[(drow+r)*64 + cf2*16 + l15],
          &outp[(size_t)50331648 + (t0 + drow + r)*64 + cf2*16 + l15]);
  stageCtx(ast0, myW, 0, 768, w, lane);   // prime A; wst0 already holds WoI[0]
  __syncthreads();

  // ======== phase 2: Wo-GEMM ctx(hole2) @ Wo -> ctxo(hole1) ========
  #pragma unroll 1
  for (int nb=0; nb<6; ++nb){
    f32x4 oa[8];
    #pragma unroll
    for (int i=0;i<8;++i) oa[i]=(f32x4){0.f,0.f,0.f,0.f};
    #pragma unroll
    for (int kb2=0; kb2<6; ++kb2){
      short* wc = (kb2&1)? wst1 : wst0;
      short* wn = (kb2&1)? wst0 : wst1;
      short* ac = (kb2&1)? ast1 : ast0;
      short* an = (kb2&1)? ast0 : ast1;
      if (kb2<5){
        stageW(wn, WoI + (size_t)(nb*6+kb2+1)*16384, w, lane);
        stageCtx(an, myW, kb2+1, 768, w, lane);
      } else if (nb<5){
        stageW(wn, WoI + (size_t)((nb+1)*6)*16384, w, lane);
        stageCtx(an, myW, 0, 768, w, lane);
      } else {
        stageW(wn, WaI, w, lane);          // prime gate pass A block (0,0)
      }
      #pragma unroll
      for (int ks=0; ks<4; ++ks){
        bf16x8 a = *(const bf16x8*)&ac[swz(arow, ks*32+g*8, 128)];
        #pragma unroll
        for (int nt=0; nt<8; ++nt)
          oa[nt] = MFMA(a, *(const bf16x8*)&wc[swz(nt*16+l15, ks*32+g*8, 128)], oa[nt]);
      }
      __syncthreads();
    }
    #pragma unroll
    for (int nt=0; nt<8; ++nt){
      int col = nb*128 + nt*16 + l15;
      float bb = bo[col];
      #pragma unroll
      for (int r=0; r<4; ++r)
        myW[(size_t)(drow+r)*1536 + col] = (u16)f2bf(oa[nt][r] + bb);
    }
  }

  // ======== phase 3: gate MLP (pass A: af regs; pass B: ctxo from hole1) ========
  float gp[4] = {0.f,0.f,0.f,0.f};
  #pragma unroll 1
  for (int nb=0; nb<6; ++nb){
    f32x4 acc[8];
    #pragma unroll
    for (int i=0;i<8;++i) acc[i]=(f32x4){0.f,0.f,0.f,0.f};
    // pass A: hs(af) @ Wg1a
    #pragma unroll
    for (int kb2=0; kb2<6; ++kb2){
      short* wc = (kb2&1)? wst1 : wst0;
      short* wn = (kb2&1)? wst0 : wst1;
      if (kb2<5) stageW(wn, WaI + (size_t)(nb*6+kb2+1)*16384, w, lane);
      else {
        stageW(wn, WbI + (size_t)(nb*6)*16384, w, lane);
        if (nb==0) stageCtx(ast0, myW, 0, 0, w, lane);   // nb>0: primed by prev pass B
      }
      #pragma unroll
      for (int ks=0; ks<4; ++ks){
        bf16x8 a = af[kb2*4+ks];
        #pragma unroll
        for (int nt=0; nt<8; ++nt)
          acc[nt] = MFMA(a, *(const bf16x8*)&wc[swz(nt*16+l15, ks*32+g*8, 128)], acc[nt]);
      }
      __syncthreads();
    }
    // pass B: ctxo(hole1) @ Wg1b
    #pragma unroll
    for (int kb2=0; kb2<6; ++kb2){
      short* wc = (kb2&1)? wst1 : wst0;
      short* wn = (kb2&1)? wst0 : wst1;
      short* ac = (kb2&1)? ast1 : ast0;
      short* an = (kb2&1)? ast0 : ast1;
      if (kb2<5){
        stageW(wn, WbI + (size_t)(nb*6+kb2+1)*16384, w, lane);
        stageCtx(an, myW, kb2+1, 0, w, lane);
      } else if (nb<5){
        stageW(wn, WaI + (size_t)((nb+1)*6)*16384, w, lane);
        stageCtx(an, myW, 0, 0, w, lane);
      }
      #pragma unroll
      for (int ks=0; ks<4; ++ks){
        bf16x8 a = *(const bf16x8*)&ac[swz(arow, ks*32+g*8, 128)];
        #pragma unroll
        for (int nt=0; nt<8; ++nt)
          acc[nt] = MFMA(a, *(const bf16x8*)&wc[swz(nt*16+l15, ks*32+g*8, 128)], acc[nt]);
      }
      __syncthreads();
    }
    #pragma unroll
    for (int nt=0; nt<8; ++nt){
      int col = nb*128 + nt*16 + l15;
      float b1 = bg1[col] + relb*wg1c[col];
      float w2 = Wg2[col];
      #pragma unroll
      for (int r=0; r<4; ++r)
        gp[r] += fmaxf(acc[nt][r] + b1, 0.f) * w2;
    }
  }
  #pragma unroll
  for (int m=1; m<16; m<<=1){
    gp[0]+=__shfl_xor(gp[0],m); gp[1]+=__shfl_xor(gp[1],m);
    gp[2]+=__shfl_xor(gp[2],m); gp[3]+=__shfl_xor(gp[3],m);
  }
  float bg2v = bg2[0];
  if (l15 == 0){
    #pragma unroll
    for (int r=0; r<4; ++r)
      gl[drow + r] = 1.f/(1.f + __expf(-(gp[r] + bg2v)));
  }
  __syncthreads();

  // ======== phase 4: residual + LayerNorm (af overwritten with x=hs+g*ctxo as bf16) ========
  {
    float gg = gl[arow];
    float sum=0.f, sq=0.f;
    #pragma unroll
    for (int kk=0; kk<24; ++kk){
      bf16x8 cv = *(const bf16x8*)&myW[(size_t)arow*1536 + kk*32 + g*8];
      bf16x8 xb;
      #pragma unroll
      for (int j=0; j<8; ++j){
        float x = bf2f(af[kk][j]) + gg * bf2f(cv[j]);
        xb[j] = f2bf(x);
        sum += x; sq += x*x;
      }
      af[kk] = xb;
    }
    sum += __shfl_xor(sum,16); sum += __shfl_xor(sum,32);
    sq  += __shfl_xor(sq,16);  sq  += __shfl_xor(sq,32);
    float mu = sum * (1.f/768.f);
    float var = sq * (1.f/768.f) - mu*mu;
    float rs = rsqrtf(var + 1e-5f);
    size_t rb = (size_t)(t0 + arow)*768;
    #pragma unroll
    for (int kk=0; kk<24; ++kk){
      int c0 = kk*32 + g*8;
      f32x4 ga = *(const f32x4*)&lng[c0], gb = *(const f32x4*)&lng[c0+4];
      f32x4 ba = *(const f32x4*)&lnb[c0], bb = *(const f32x4*)&lnb[c0+4];
      f32x4 o0, o1;
      #pragma unroll
      for (int j=0;j<4;++j)
        o0[j] = (bf2f(af[kk][j]) - mu)*rs*ga[j] + ba[j];
      #pragma unroll
      for (int j=0;j<4;++j)
        o1[j] = (bf2f(af[kk][4+j]) - mu)*rs*gb[j] + bb[j];
      __builtin_nontemporal_store(o0, (f32x4*)&outp[rb + c0]);
      __builtin_nontemporal_store(o1, (f32x4*)&outp[rb + c0 + 4]);
    }
  }
}

extern "C" void kernel_launch(void* const* d_in, const int* in_sizes, int n_in,
                              void* d_out, int out_size, void* d_ws, size_t ws_size,
                              hipStream_t stream) {
  (void)in_sizes; (void)n_in; (void)out_size; (void)ws_size;
  const float* hs  = (const float*)d_in[0];
  const float* ce  = (const float*)d_in[1];
  const float* Wq  = (const float*)d_in[2];
  const float* bq  = (const float*)d_in[3];
  const float* Wk  = (const float*)d_in[4];
  const float* bk  = (const float*)d_in[5];
  const float* Wv  = (const float*)d_in[6];
  const float* bv  = (const float*)d_in[7];
  const float* Wo  = (const float*)d_in[8];
  const float* bo  = (const float*)d_in[9];
  const float* Wg1 = (const float*)d_in[10];
  const float* bg1 = (const float*)d_in[11];
  const float* Wg2 = (const float*)d_in[12];
  const float* bg2 = (const float*)d_in[13];
  const float* lng = (const float*)d_in[14];
  const float* lnb = (const float*)d_in[15];
  char* ws = (char*)d_ws;
  short* WqI  = (short*)(ws + 0);
  short* WoI  = (short*)(ws + 1179648);
  short* WaI  = (short*)(ws + 2359296);
  short* WbI  = (short*)(ws + 3538944);
  short* Kc   = (short*)(ws + 4718592);
  short* VT   = (short*)(ws + 4816896);
  float* wg1c = (float*)(ws + 4915200);
  float* cp   = (float*)(ws + 4918272);
  float* tp   = (float*)(ws + 4921344);
  float* rel  = (float*)(ws + 4970496);
  float* tpp  = (float*)(ws + 4970752);
  float* outp = (float*)d_out;

  prep_w   <<<144, 256, 0, stream>>>(Wq, Wo, Wg1, WqI, WoI, WaI, WbI);
  prep_kv  <<<8,   768, 0, stream>>>(ce, Wk, bk, Wv, bv, Kc, VT);
  prep_misc<<<6,   256, 0, stream>>>(Wg1, ce, wg1c, cp);
  pool1    <<<512, 256, 0, stream>>>(hs, tpp);
  pool2    <<<48,  256, 0, stream>>>(tpp, tp);
  pool3    <<<16,  256, 0, stream>>>(tp, cp, rel);
  hipFuncSetAttribute(reinterpret_cast<const void*>(fused),
                      hipFuncAttributeMaxDynamicSharedMemorySize, 147456);
  fused<<<512, 512, 147456, stream>>>(hs, WqI, WoI, WaI, WbI, Kc, VT, bq, bo,
                                      bg1, wg1c, Wg2, bg2, rel, lng, lnb, outp);
}

// Round 7
// 1140.942 us; speedup vs baseline: 1.4654x; 1.4654x over previous
//
#include <hip/hip_runtime.h>

typedef __attribute__((ext_vector_type(8))) short bf16x8;
typedef __attribute__((ext_vector_type(4))) float f32x4;
typedef unsigned short u16;

#define MFMA(a,b,c) __builtin_amdgcn_mfma_f32_16x16x32_bf16((a),(b),(c),0,0,0)

__device__ __forceinline__ short f2bf(float f){
  union { float f; unsigned u; } v; v.f = f;
  unsigned r = v.u + 0x7FFFu + ((v.u >> 16) & 1u);
  return (short)(r >> 16);
}
__device__ __forceinline__ float bf2f(short s){
  union { unsigned u; float f; } v; v.u = ((unsigned)(unsigned short)s) << 16; return v.f;
}
__device__ __forceinline__ bf16x8 pack8(f32x4 x, f32x4 y){
  bf16x8 r;
  r[0]=f2bf(x[0]); r[1]=f2bf(x[1]); r[2]=f2bf(x[2]); r[3]=f2bf(x[3]);
  r[4]=f2bf(y[0]); r[5]=f2bf(y[1]); r[6]=f2bf(y[2]); r[7]=f2bf(y[3]);
  return r;
}
// attb LDS swizzle (16B-chunk granularity)
__device__ __forceinline__ int swz(int row, int col, int rowShorts){
  int byte = col << 1;
  int chunk = (byte & ~15) ^ ((row & 7) << 4);
  return row * rowShorts + ((chunk | (byte & 15)) >> 1);
}
// hole swizzle: physical 16B-chunk index for logical chunk c of row
__device__ __forceinline__ int pch(int c, int row){ return (c & ~7) | ((c & 7) ^ (row & 7)); }

__device__ __forceinline__ void gload16(void* lp, const void* gp){
  __builtin_amdgcn_global_load_lds((const __attribute__((address_space(1))) unsigned*)gp,
                                   (__attribute__((address_space(3))) unsigned*)lp, 16, 0, 0);
}
// stage 16KB weight half-block: 128 rows x 8 chunks (k-half of a [128][128] image block)
__device__ __forceinline__ void stWB(short* buf, const short* img, int half, int w, int lane){
  const char* gp = (const char*)img;
  #pragma unroll
  for (int it=0; it<4; ++it){
    int id = it*256 + w*64 + lane; int r = id>>3, c = id&7;
    gload16((char*)buf + it*4096 + w*1024, gp + r*256 + half*128 + c*16);
  }
}
// stage 16KB A-tile: 128 rows x 8 chunks from pre-swizzled hole (rowb pre-offset to hole)
__device__ __forceinline__ void stA128(short* buf, const u16* rowb, int kstep, int w, int lane){
  #pragma unroll
  for (int it=0; it<4; ++it){
    int id = it*256 + w*64 + lane; int r = id>>3, c = id&7;
    gload16((char*)buf + it*4096 + w*1024, rowb + (size_t)r*1536 + (kstep*8 + c)*8);
  }
}

// ---------------- prep kernels ----------------
__global__ void prep_w(const float* __restrict__ Wq, const float* __restrict__ Wo,
                       const float* __restrict__ Wg1, short* __restrict__ WqI,
                       short* __restrict__ WoI, short* __restrict__ WaI, short* __restrict__ WbI){
  __shared__ short lt[128][136];
  int blk = blockIdx.x;            // 144 = 4 mats * 6 ktiles * 6 jtiles
  int mat = blk / 36, t = blk % 36, kt = t / 6, jt = t % 6;
  const float* src = (mat==0)? Wq : (mat==1)? Wo : (mat==2)? Wg1 : (Wg1 + (size_t)768*768);
  short* dst = (mat==0)? WqI : (mat==1)? WoI : (mat==2)? WaI : WbI;
  int tid = threadIdx.x;           // 256
  for (int it=0; it<64; ++it){
    int idx = it*256 + tid;
    int kl = idx >> 7, jl = idx & 127;
    lt[jl][kl] = f2bf(src[(size_t)(kt*128+kl)*768 + jt*128 + jl]);
  }
  __syncthreads();
  size_t base = (size_t)(jt*6 + kt)*16384;
  for (int cc=0; cc<8; ++cc){
    int ci = cc*256 + tid;
    int jl = ci >> 4, sc = ci & 15;
    int kkb = ((sc ^ (jl & 7)) << 3);
    bf16x8 v = *(const bf16x8*)&lt[jl][kkb];
    *(bf16x8*)&dst[base + (size_t)jl*128 + sc*8] = v;
  }
}

__global__ void prep_kv(const float* __restrict__ ce, const float* __restrict__ Wk,
                        const float* __restrict__ bk, const float* __restrict__ Wv,
                        const float* __restrict__ bv, short* __restrict__ Kc, short* __restrict__ VT){
  __shared__ float sh[8][768];
  int c0 = blockIdx.x*8, j = threadIdx.x;   // 8 blocks x 768 threads
  #pragma unroll
  for (int c2=0; c2<8; ++c2) sh[c2][j] = ce[(size_t)(c0+c2)*768 + j];
  __syncthreads();
  float aK[8], aV[8];
  float bkj = bk[j], bvj = bv[j];
  #pragma unroll
  for (int c2=0; c2<8; ++c2){ aK[c2]=bkj; aV[c2]=bvj; }
  for (int h=0; h<768; ++h){
    float wk = Wk[(size_t)h*768+j], wv = Wv[(size_t)h*768+j];
    #pragma unroll
    for (int c2=0; c2<8; ++c2){ float x = sh[c2][h]; aK[c2] += x*wk; aV[c2] += x*wv; }
  }
  #pragma unroll
  for (int c2=0; c2<8; ++c2){
    Kc[(size_t)(c0+c2)*768 + j] = f2bf(aK[c2]);
    VT[(size_t)j*64 + c0+c2] = f2bf(aV[c2]);
  }
}

__global__ void prep_misc(const float* __restrict__ Wg1, const float* __restrict__ ce,
                          float* __restrict__ wg1c, float* __restrict__ cp){
  int i = blockIdx.x*256 + threadIdx.x;   // 0..1535
  if (blockIdx.x < 3){
    int j = i; float s = 0.f;
    for (int r=0; r<768; ++r) s += Wg1[(size_t)(1536+r)*768 + j];
    wg1c[j] = s;
  } else {
    int h = i - 768; float s = 0.f;
    for (int c2=0; c2<64; ++c2) s += ce[(size_t)c2*768 + h];
    cp[h] = s * (1.f/64.f);
  }
}

__global__ void pool1(const float* __restrict__ hs, float* __restrict__ tpp){
  int b = blockIdx.x >> 5, sc = blockIdx.x & 31;
  size_t base = ((size_t)b*4096 + (size_t)sc*128)*768;
  for (int h = threadIdx.x; h < 768; h += 256){
    float s = 0.f;
    #pragma unroll 4
    for (int s2=0; s2<128; ++s2) s += __builtin_nontemporal_load(&hs[base + (size_t)s2*768 + h]);
    tpp[(size_t)blockIdx.x*768 + h] = s;
  }
}
__global__ void pool2(const float* __restrict__ tpp, float* __restrict__ tp){
  int b = blockIdx.x / 3, hc = blockIdx.x % 3;
  int h = hc*256 + threadIdx.x;
  float s = 0.f;
  for (int k=0; k<32; ++k) s += tpp[((size_t)b*32 + k)*768 + h];
  tp[(size_t)b*768 + h] = s * (1.f/4096.f);
}
__global__ void pool3(const float* __restrict__ tp, const float* __restrict__ cp, float* __restrict__ rel){
  int b = blockIdx.x;
  float a=0.f, n1=0.f, n2=0.f;
  for (int h = threadIdx.x; h < 768; h += 256){
    float t = tp[(size_t)b*768 + h], c = cp[h];
    a += t*c; n1 += t*t; n2 += c*c;
  }
  #pragma unroll
  for (int m=1; m<64; m<<=1){ a+=__shfl_xor(a,m); n1+=__shfl_xor(n1,m); n2+=__shfl_xor(n2,m); }
  __shared__ float r3[3][4];
  int w = threadIdx.x >> 6;
  if ((threadIdx.x & 63) == 0){ r3[0][w]=a; r3[1][w]=n1; r3[2][w]=n2; }
  __syncthreads();
  if (threadIdx.x == 0){
    float A = r3[0][0]+r3[0][1]+r3[0][2]+r3[0][3];
    float N1= r3[1][0]+r3[1][1]+r3[1][2]+r3[1][3];
    float N2= r3[2][0]+r3[2][1]+r3[2][2]+r3[2][3];
    rel[b] = A / (fmaxf(sqrtf(N1),1e-8f) * fmaxf(sqrtf(N2),1e-8f));
  }
}

// hs f32 -> bf16, pre-swizzled, into hole1 [0,768) of each d_out row
__global__ __launch_bounds__(256) void prep_hs(const float* __restrict__ hs, float* __restrict__ outp){
  int tid = threadIdx.x;
  size_t r0 = (size_t)blockIdx.x*8;
  u16* holes = (u16*)outp;
  #pragma unroll
  for (int it=0; it<3; ++it){
    int idx = it*256 + tid;      // 0..767 = 8 rows x 96 chunks
    int lr = idx/96, c = idx - lr*96;
    size_t row = r0 + lr;
    const float* p = hs + row*768 + c*8;
    f32x4 x = __builtin_nontemporal_load((const f32x4*)p);
    f32x4 y = __builtin_nontemporal_load((const f32x4*)(p+4));
    *(bf16x8*)&holes[row*1536 + pch(c,(int)row)*8] = pack8(x,y);
  }
}

// ---------------- gq: Q = scale*(hs @ Wq + bq) -> hole2 ----------------
__global__ __launch_bounds__(256) void gq(const short* __restrict__ WqI,
                                          const float* __restrict__ bq, float* outp){
  __shared__ short A0[8192], A1[8192], B0[8192], B1[8192];
  const int tid = threadIdx.x, lane = tid & 63, w = tid >> 6;
  const int l15 = lane & 15, g = lane >> 4;
  const int nb = blockIdx.x >> 9, mt = blockIdx.x & 511;   // nb-major
  const int wm = w & 1, wn = w >> 1;
  const size_t t0 = (size_t)mt*128;
  u16* holes = (u16*)outp;
  const u16* Arow = holes + t0*1536;                 // hole1
  const short* Wimg = WqI + (size_t)nb*6*16384;
  f32x4 acc[4][4];
  #pragma unroll
  for (int i=0;i<4;++i)
    #pragma unroll
    for (int j=0;j<4;++j) acc[i][j] = (f32x4){0.f,0.f,0.f,0.f};
  stA128(A0, Arow, 0, w, lane);
  stWB(B0, Wimg, 0, w, lane);
  __syncthreads();
  #pragma unroll
  for (int ks2=0; ks2<12; ++ks2){
    const short* Ac = (ks2&1)? A1 : A0;
    const short* Bc = (ks2&1)? B1 : B0;
    short* An = (ks2&1)? A0 : A1;
    short* Bn = (ks2&1)? B0 : B1;
    if (ks2<11){
      stA128(An, Arow, ks2+1, w, lane);
      stWB(Bn, Wimg + (size_t)(((ks2+1)>>1))*16384, (ks2+1)&1, w, lane);
    }
    #pragma unroll
    for (int ks=0; ks<2; ++ks){
      bf16x8 a[4], b[4];
      #pragma unroll
      for (int mf=0; mf<4; ++mf){ int r = wm*64+mf*16+l15; a[mf] = *(const bf16x8*)&Ac[r*64 + (((ks*4+g)^(r&7))<<3)]; }
      #pragma unroll
      for (int nf=0; nf<4; ++nf){ int r = wn*64+nf*16+l15; b[nf] = *(const bf16x8*)&Bc[r*64 + (((ks*4+g)^(r&7))<<3)]; }
      #pragma unroll
      for (int mf=0; mf<4; ++mf)
        #pragma unroll
        for (int nf=0; nf<4; ++nf)
          acc[mf][nf] = MFMA(a[mf], b[nf], acc[mf][nf]);
    }
    __syncthreads();
  }
  #pragma unroll
  for (int mf=0; mf<4; ++mf)
    #pragma unroll
    for (int nf=0; nf<4; ++nf)
      #pragma unroll
      for (int r=0; r<4; ++r){
        int grow = wm*64 + mf*16 + g*4 + r;
        int col = nb*128 + wn*64 + nf*16 + l15;
        float v = (acc[mf][nf][r] + bq[col]) * 0.10206207262f;
        holes[(t0+grow)*1536 + 768 + pch(col>>3, grow)*8 + (col&7)] = (u16)f2bf(v);
      }
}

// ---------------- att: attention from Q(hole2) -> ctx(hole2) + attn_avg ----------------
__global__ __launch_bounds__(256) void att(const short* __restrict__ Kc,
                                           const short* __restrict__ VT, float* outp){
  __shared__ short attb[4096];   // [64][64] swz
  const int tid = threadIdx.x, lane = tid & 63, w = tid >> 6;
  const int l15 = lane & 15, g = lane >> 4;
  const size_t t0 = (size_t)blockIdx.x * 64;
  const int arow = w*16 + l15;
  const int drow = w*16 + g*4;
  u16* holes = (u16*)outp;
  float aavg[16];
  #pragma unroll
  for (int i=0;i<16;++i) aavg[i]=0.f;

  #pragma unroll 1
  for (int h=0; h<8; ++h){
    f32x4 sa[4];
    #pragma unroll
    for (int i=0;i<4;++i) sa[i]=(f32x4){0.f,0.f,0.f,0.f};
    #pragma unroll
    for (int ks=0; ks<3; ++ks){
      int kc = 12*h + ks*4 + g;
      bf16x8 a = *(const bf16x8*)&holes[(t0+arow)*1536 + 768 + pch(kc, arow)*8];
      #pragma unroll
      for (int cf2=0; cf2<4; ++cf2)
        sa[cf2] = MFMA(a, *(const bf16x8*)&Kc[(size_t)(cf2*16+l15)*768 + h*96 + ks*32 + g*8], sa[cf2]);
    }
    #pragma unroll
    for (int r=0; r<4; ++r){
      float v0=sa[0][r], v1=sa[1][r], v2=sa[2][r], v3=sa[3][r];
      float m = fmaxf(fmaxf(v0,v1),fmaxf(v2,v3));
      m = fmaxf(m,__shfl_xor(m,1)); m = fmaxf(m,__shfl_xor(m,2));
      m = fmaxf(m,__shfl_xor(m,4)); m = fmaxf(m,__shfl_xor(m,8));
      float e0=__expf(v0-m),e1=__expf(v1-m),e2=__expf(v2-m),e3=__expf(v3-m);
      float s=e0+e1+e2+e3;
      s+=__shfl_xor(s,1); s+=__shfl_xor(s,2); s+=__shfl_xor(s,4); s+=__shfl_xor(s,8);
      float inv = 1.f/s;
      e0*=inv; e1*=inv; e2*=inv; e3*=inv;
      attb[swz(drow+r,  0+l15, 64)] = f2bf(e0);
      attb[swz(drow+r, 16+l15, 64)] = f2bf(e1);
      attb[swz(drow+r, 32+l15, 64)] = f2bf(e2);
      attb[swz(drow+r, 48+l15, 64)] = f2bf(e3);
      aavg[0+r]+=e0*0.125f; aavg[4+r]+=e1*0.125f; aavg[8+r]+=e2*0.125f; aavg[12+r]+=e3*0.125f;
    }
    // PV -> ctx bf16 (overwrites this head's Q cols; reads of them are done)
    {
      f32x4 pv[6];
      #pragma unroll
      for (int i=0;i<6;++i) pv[i]=(f32x4){0.f,0.f,0.f,0.f};
      #pragma unroll
      for (int ks=0; ks<2; ++ks){
        bf16x8 a = *(const bf16x8*)&attb[swz(arow, ks*32+g*8, 64)];
        #pragma unroll
        for (int nt=0; nt<6; ++nt)
          pv[nt] = MFMA(a, *(const bf16x8*)&VT[(size_t)(h*96 + nt*16 + l15)*64 + ks*32 + g*8], pv[nt]);
      }
      #pragma unroll
      for (int nt=0; nt<6; ++nt)
        #pragma unroll
        for (int r=0; r<4; ++r){
          int row = drow + r;
          int col = h*96 + nt*16 + l15;
          holes[(t0+row)*1536 + 768 + pch(col>>3, row)*8 + (col&7)] = (u16)f2bf(pv[nt][r]);
        }
    }
  }
  #pragma unroll
  for (int cf2=0; cf2<4; ++cf2)
    #pragma unroll
    for (int r=0; r<4; ++r)
      __builtin_nontemporal_store(aavg[cf2*4+r],
          &outp[(size_t)50331648 + (t0 + drow + r)*64 + cf2*16 + l15]);
}

// ---------------- gwo: ctxo = ctx @ Wo + bo -> hole2 (ctx held in regs first) ----------------
__global__ __launch_bounds__(256) void gwo(const short* __restrict__ WoI,
                                           const float* __restrict__ bo, float* outp){
  __shared__ short B0[8192], B1[8192];
  const int tid = threadIdx.x, lane = tid & 63, w = tid >> 6;
  const int l15 = lane & 15, g = lane >> 4;
  const size_t t0 = (size_t)blockIdx.x * 64;
  const int arow = w*16 + l15;
  const int drow = w*16 + g*4;
  u16* holes = (u16*)outp;
  bf16x8 af[24];
  #pragma unroll
  for (int kk=0; kk<24; ++kk){
    int kc = kk*4 + g;
    af[kk] = *(const bf16x8*)&holes[(t0+arow)*1536 + 768 + pch(kc, arow)*8];
  }
  stWB(B0, WoI, 0, w, lane);
  __syncthreads();
  #pragma unroll 1
  for (int nb=0; nb<6; ++nb){
    f32x4 acc[8];
    #pragma unroll
    for (int i=0;i<8;++i) acc[i]=(f32x4){0.f,0.f,0.f,0.f};
    #pragma unroll
    for (int ks2=0; ks2<12; ++ks2){
      const short* Bc = (ks2&1)? B1 : B0;
      short* Bn = (ks2&1)? B0 : B1;
      if (ks2<11)      stWB(Bn, WoI + (size_t)(nb*6 + ((ks2+1)>>1))*16384, (ks2+1)&1, w, lane);
      else if (nb<5)   stWB(Bn, WoI + (size_t)((nb+1)*6)*16384, 0, w, lane);
      #pragma unroll
      for (int ks=0; ks<2; ++ks){
        bf16x8 a = af[ks2*2 + ks];
        #pragma unroll
        for (int nf=0; nf<8; ++nf){
          int br = nf*16 + l15;
          bf16x8 b = *(const bf16x8*)&Bc[br*64 + (((ks*4+g)^(br&7))<<3)];
          acc[nf] = MFMA(a, b, acc[nf]);
        }
      }
      __syncthreads();
    }
    #pragma unroll
    for (int nf=0; nf<8; ++nf)
      #pragma unroll
      for (int r=0; r<4; ++r){
        int row = drow + r;
        int col = nb*128 + nf*16 + l15;
        float v = acc[nf][r] + bo[col];
        holes[(t0+row)*1536 + 768 + pch(col>>3, row)*8 + (col&7)] = (u16)f2bf(v);
      }
  }
}

// ---------------- gate_k: gate = sigmoid(relu([hs,ctxo,rel]@Wg1+bg1)@Wg2+bg2) ----------------
__global__ __launch_bounds__(256) void gate_k(const short* __restrict__ WaI,
    const short* __restrict__ WbI, const float* __restrict__ bg1,
    const float* __restrict__ wg1c, const float* __restrict__ Wg2,
    const float* __restrict__ bg2, const float* __restrict__ rel,
    float* __restrict__ gateArr, float* outp){
  __shared__ short A0[8192], A1[8192], B0[8192], B1[8192];
  const int tid = threadIdx.x, lane = tid & 63, w = tid >> 6;
  const int l15 = lane & 15, g = lane >> 4;
  const int wm = w & 1, wn = w >> 1;
  const size_t t0 = (size_t)blockIdx.x * 128;
  const float relb = rel[t0 >> 12];
  u16* holes = (u16*)outp;
  const u16* h1p = holes + t0*1536;        // hs_bf16
  const u16* h2p = holes + t0*1536 + 768;  // ctxo
  float gp[4][4];
  #pragma unroll
  for (int i=0;i<4;++i)
    #pragma unroll
    for (int j=0;j<4;++j) gp[i][j]=0.f;
  stA128(A0, h1p, 0, w, lane);
  stWB(B0, WaI, 0, w, lane);
  __syncthreads();
  #pragma unroll 1
  for (int nb=0; nb<6; ++nb){
    f32x4 acc[4][4];
    #pragma unroll
    for (int i=0;i<4;++i)
      #pragma unroll
      for (int j=0;j<4;++j) acc[i][j]=(f32x4){0.f,0.f,0.f,0.f};
    #pragma unroll
    for (int pass=0; pass<2; ++pass){
      const short* Wimg = pass ? WbI : WaI;
      const u16* Ap = pass ? h2p : h1p;
      #pragma unroll
      for (int ks2=0; ks2<12; ++ks2){
        const short* Ac = (ks2&1)? A1 : A0;
        const short* Bc = (ks2&1)? B1 : B0;
        short* An = (ks2&1)? A0 : A1;
        short* Bn = (ks2&1)? B0 : B1;
        if (ks2<11){
          stA128(An, Ap, ks2+1, w, lane);
          stWB(Bn, Wimg + (size_t)(nb*6 + ((ks2+1)>>1))*16384, (ks2+1)&1, w, lane);
        } else if (pass==0){
          stA128(An, h2p, 0, w, lane);
          stWB(Bn, WbI + (size_t)(nb*6)*16384, 0, w, lane);
        } else if (nb<5){
          stA128(An, h1p, 0, w, lane);
          stWB(Bn, WaI + (size_t)((nb+1)*6)*16384, 0, w, lane);
        }
        #pragma unroll
        for (int ks=0; ks<2; ++ks){
          bf16x8 a[4], b[4];
          #pragma unroll
          for (int mf=0; mf<4; ++mf){ int r = wm*64+mf*16+l15; a[mf] = *(const bf16x8*)&Ac[r*64 + (((ks*4+g)^(r&7))<<3)]; }
          #pragma unroll
          for (int nf=0; nf<4; ++nf){ int r = wn*64+nf*16+l15; b[nf] = *(const bf16x8*)&Bc[r*64 + (((ks*4+g)^(r&7))<<3)]; }
          #pragma unroll
          for (int mf=0; mf<4; ++mf)
            #pragma unroll
            for (int nf=0; nf<4; ++nf)
              acc[mf][nf] = MFMA(a[mf], b[nf], acc[mf][nf]);
        }
        __syncthreads();
      }
    }
    #pragma unroll
    for (int mf=0; mf<4; ++mf)
      #pragma unroll
      for (int nf=0; nf<4; ++nf)
        #pragma unroll
        for (int r=0; r<4; ++r){
          int col = nb*128 + wn*64 + nf*16 + l15;
          gp[mf][r] += fmaxf(acc[mf][nf][r] + bg1[col] + relb*wg1c[col], 0.f) * Wg2[col];
        }
  }
  #pragma unroll
  for (int mf=0; mf<4; ++mf)
    #pragma unroll
    for (int r=0; r<4; ++r){
      float v = gp[mf][r];
      v += __shfl_xor(v,1); v += __shfl_xor(v,2); v += __shfl_xor(v,4); v += __shfl_xor(v,8);
      gp[mf][r] = v;
    }
  __syncthreads();
  float* gred = (float*)B0;   // B0 dead now
  if (l15 == 0)
    #pragma unroll
    for (int mf=0; mf<4; ++mf)
      #pragma unroll
      for (int r=0; r<4; ++r)
        gred[wn*128 + wm*64 + mf*16 + g*4 + r] = gp[mf][r];
  __syncthreads();
  if (tid < 128)
    gateArr[t0 + tid] = 1.f/(1.f + __expf(-(gred[tid] + gred[128+tid] + bg2[0])));
}

// ---------------- lnk: out = LN(hs + gate*ctxo) ----------------
__global__ __launch_bounds__(256) void lnk(const float* __restrict__ gateArr,
    const float* __restrict__ lng, const float* __restrict__ lnb, float* outp){
  const int tid = threadIdx.x, lane = tid & 63, w = tid >> 6;
  u16* holes = (u16*)outp;
  #pragma unroll 1
  for (int i=0; i<8; ++i){
    int row = blockIdx.x*32 + w*8 + i;
    float gg = gateArr[row];
    int c1 = lane, c2 = 64 + (lane & 31);
    size_t rb = (size_t)row*1536;
    bf16x8 hv1 = *(const bf16x8*)&holes[rb + pch(c1,row)*8];
    bf16x8 ov1 = *(const bf16x8*)&holes[rb + 768 + pch(c1,row)*8];
    bf16x8 hv2 = *(const bf16x8*)&holes[rb + pch(c2,row)*8];
    bf16x8 ov2 = *(const bf16x8*)&holes[rb + 768 + pch(c2,row)*8];
    float x1[8], x2[8];
    float sum=0.f, sq=0.f;
    #pragma unroll
    for (int j=0;j<8;++j){ float x = bf2f(hv1[j]) + gg*bf2f(ov1[j]); x1[j]=x; sum+=x; sq+=x*x; }
    if (lane < 32){
      #pragma unroll
      for (int j=0;j<8;++j){ float x = bf2f(hv2[j]) + gg*bf2f(ov2[j]); x2[j]=x; sum+=x; sq+=x*x; }
    }
    #pragma unroll
    for (int m=1; m<64; m<<=1){ sum += __shfl_xor(sum,m); sq += __shfl_xor(sq,m); }
    float mu = sum * (1.f/768.f);
    float var = sq * (1.f/768.f) - mu*mu;
    float rs = rsqrtf(var + 1e-5f);
    {
      f32x4 ga = *(const f32x4*)&lng[c1*8], gb = *(const f32x4*)&lng[c1*8+4];
      f32x4 ba = *(const f32x4*)&lnb[c1*8], bb = *(const f32x4*)&lnb[c1*8+4];
      f32x4 o0, o1;
      #pragma unroll
      for (int j=0;j<4;++j){ o0[j] = (x1[j]-mu)*rs*ga[j]+ba[j]; o1[j] = (x1[4+j]-mu)*rs*gb[j]+bb[j]; }
      *(f32x4*)&outp[(size_t)row*768 + c1*8] = o0;
      *(f32x4*)&outp[(size_t)row*768 + c1*8 + 4] = o1;
    }
    if (lane < 32){
      f32x4 ga = *(const f32x4*)&lng[c2*8], gb = *(const f32x4*)&lng[c2*8+4];
      f32x4 ba = *(const f32x4*)&lnb[c2*8], bb = *(const f32x4*)&lnb[c2*8+4];
      f32x4 o0, o1;
      #pragma unroll
      for (int j=0;j<4;++j){ o0[j] = (x2[j]-mu)*rs*ga[j]+ba[j]; o1[j] = (x2[4+j]-mu)*rs*gb[j]+bb[j]; }
      *(f32x4*)&outp[(size_t)row*768 + c2*8] = o0;
      *(f32x4*)&outp[(size_t)row*768 + c2*8 + 4] = o1;
    }
  }
}

extern "C" void kernel_launch(void* const* d_in, const int* in_sizes, int n_in,
                              void* d_out, int out_size, void* d_ws, size_t ws_size,
                              hipStream_t stream) {
  (void)in_sizes; (void)n_in; (void)out_size; (void)ws_size;
  const float* hs  = (const float*)d_in[0];
  const float* ce  = (const float*)d_in[1];
  const float* Wq  = (const float*)d_in[2];
  const float* bq  = (const float*)d_in[3];
  const float* Wk  = (const float*)d_in[4];
  const float* bk  = (const float*)d_in[5];
  const float* Wv  = (const float*)d_in[6];
  const float* bv  = (const float*)d_in[7];
  const float* Wo  = (const float*)d_in[8];
  const float* bo  = (const float*)d_in[9];
  const float* Wg1 = (const float*)d_in[10];
  const float* bg1 = (const float*)d_in[11];
  const float* Wg2 = (const float*)d_in[12];
  const float* bg2 = (const float*)d_in[13];
  const float* lng = (const float*)d_in[14];
  const float* lnb = (const float*)d_in[15];
  char* ws = (char*)d_ws;
  short* WqI   = (short*)(ws + 0);
  short* WoI   = (short*)(ws + 1179648);
  short* WaI   = (short*)(ws + 2359296);
  short* WbI   = (short*)(ws + 3538944);
  short* Kc    = (short*)(ws + 4718592);
  short* VT    = (short*)(ws + 4816896);
  float* wg1c  = (float*)(ws + 4915200);
  float* cp    = (float*)(ws + 4918272);
  float* tp    = (float*)(ws + 4921344);
  float* rel   = (float*)(ws + 4970496);
  float* tpp   = (float*)(ws + 4970752);
  float* gateA = (float*)(ws + 6543616);
  float* outp  = (float*)d_out;

  prep_w   <<<144, 256, 0, stream>>>(Wq, Wo, Wg1, WqI, WoI, WaI, WbI);
  prep_kv  <<<8,   768, 0, stream>>>(ce, Wk, bk, Wv, bv, Kc, VT);
  prep_misc<<<6,   256, 0, stream>>>(Wg1, ce, wg1c, cp);
  pool1    <<<512, 256, 0, stream>>>(hs, tpp);
  pool2    <<<48,  256, 0, stream>>>(tpp, tp);
  pool3    <<<16,  256, 0, stream>>>(tp, cp, rel);
  prep_hs  <<<8192,256, 0, stream>>>(hs, outp);
  gq       <<<3072,256, 0, stream>>>(WqI, bq, outp);
  att      <<<1024,256, 0, stream>>>(Kc, VT, outp);
  gwo      <<<1024,256, 0, stream>>>(WoI, bo, outp);
  gate_k   <<<512, 256, 0, stream>>>(WaI, WbI, bg1, wg1c, Wg2, bg2, rel, gateA, outp);
  lnk      <<<2048,256, 0, stream>>>(gateA, lng, lnb, outp);
}

// Round 8
// 653.540 us; speedup vs baseline: 2.5582x; 1.7458x over previous
//
#include <hip/hip_runtime.h>

typedef __attribute__((ext_vector_type(8))) short bf16x8;
typedef __attribute__((ext_vector_type(4))) float f32x4;
typedef unsigned short u16;

#define MFMA(a,b,c) __builtin_amdgcn_mfma_f32_16x16x32_bf16((a),(b),(c),0,0,0)

__device__ __forceinline__ short f2bf(float f){
  union { float f; unsigned u; } v; v.f = f;
  unsigned r = v.u + 0x7FFFu + ((v.u >> 16) & 1u);
  return (short)(r >> 16);
}
__device__ __forceinline__ float bf2f(short s){
  union { unsigned u; float f; } v; v.u = ((unsigned)(unsigned short)s) << 16; return v.f;
}
__device__ __forceinline__ bf16x8 pack8(f32x4 x, f32x4 y){
  bf16x8 r;
  r[0]=f2bf(x[0]); r[1]=f2bf(x[1]); r[2]=f2bf(x[2]); r[3]=f2bf(x[3]);
  r[4]=f2bf(y[0]); r[5]=f2bf(y[1]); r[6]=f2bf(y[2]); r[7]=f2bf(y[3]);
  return r;
}
// attb LDS swizzle (16B-chunk granularity)
__device__ __forceinline__ int swz(int row, int col, int rowShorts){
  int byte = col << 1;
  int chunk = (byte & ~15) ^ ((row & 7) << 4);
  return row * rowShorts + ((chunk | (byte & 15)) >> 1);
}
// hole swizzle: physical 16B-chunk index for logical chunk c of row
__device__ __forceinline__ int pch(int c, int row){ return (c & ~7) | ((c & 7) ^ (row & 7)); }

__device__ __forceinline__ void gload16(void* lp, const void* gp){
  __builtin_amdgcn_global_load_lds((const __attribute__((address_space(1))) unsigned*)gp,
                                   (__attribute__((address_space(3))) unsigned*)lp, 16, 0, 0);
}
// stage 16KB weight half-block: 128 rows x 8 chunks (k-half of a [128][128] image block)
__device__ __forceinline__ void stWB(short* buf, const short* img, int half, int w, int lane){
  const char* gp = (const char*)img;
  #pragma unroll
  for (int it=0; it<4; ++it){
    int id = it*256 + w*64 + lane; int r = id>>3, c = id&7;
    gload16((char*)buf + it*4096 + w*1024, gp + r*256 + half*128 + c*16);
  }
}
// stage 16KB A-tile: 128 rows x 8 chunks from pre-swizzled hole (rowb pre-offset to hole)
__device__ __forceinline__ void stA128(short* buf, const u16* rowb, int kstep, int w, int lane){
  #pragma unroll
  for (int it=0; it<4; ++it){
    int id = it*256 + w*64 + lane; int r = id>>3, c = id&7;
    gload16((char*)buf + it*4096 + w*1024, rowb + (size_t)r*1536 + (kstep*8 + c)*8);
  }
}

// ---------------- prep kernels ----------------
__global__ void prep_w(const float* __restrict__ Wq, const float* __restrict__ Wo,
                       const float* __restrict__ Wg1, short* __restrict__ WqI,
                       short* __restrict__ WoI, short* __restrict__ WaI, short* __restrict__ WbI){
  __shared__ short lt[128][136];
  int blk = blockIdx.x;            // 144 = 4 mats * 6 ktiles * 6 jtiles
  int mat = blk / 36, t = blk % 36, kt = t / 6, jt = t % 6;
  const float* src = (mat==0)? Wq : (mat==1)? Wo : (mat==2)? Wg1 : (Wg1 + (size_t)768*768);
  short* dst = (mat==0)? WqI : (mat==1)? WoI : (mat==2)? WaI : WbI;
  int tid = threadIdx.x;           // 256
  #pragma unroll
  for (int it=0; it<16; ++it){
    int kl = it*8 + (tid>>5);
    int jl = (tid&31)*4;
    f32x4 v = *(const f32x4*)&src[(size_t)(kt*128+kl)*768 + jt*128 + jl];
    lt[jl+0][kl]=f2bf(v[0]); lt[jl+1][kl]=f2bf(v[1]);
    lt[jl+2][kl]=f2bf(v[2]); lt[jl+3][kl]=f2bf(v[3]);
  }
  __syncthreads();
  size_t base = (size_t)(jt*6 + kt)*16384;
  #pragma unroll
  for (int cc=0; cc<8; ++cc){
    int ci = cc*256 + tid;
    int jl = ci >> 4, sc = ci & 15;
    int kkb = ((sc ^ (jl & 7)) << 3);
    bf16x8 v = *(const bf16x8*)&lt[jl][kkb];
    *(bf16x8*)&dst[base + (size_t)jl*128 + sc*8] = v;
  }
}

// 96 blocks = 12 j-tiles(64 cols) x 8 concept-groups(8 concepts)
__global__ __launch_bounds__(256) void prep_kv(const float* __restrict__ ce,
                        const float* __restrict__ Wk, const float* __restrict__ bk,
                        const float* __restrict__ Wv, const float* __restrict__ bv,
                        short* __restrict__ Kc, short* __restrict__ VT){
  __shared__ float sh[8][768];
  int jt = blockIdx.x / 8, cg = blockIdx.x % 8;
  int tid = threadIdx.x;
  int j = jt*64 + (tid & 63);
  int cl = tid >> 6;               // 0..3, 2 concepts each
  for (int i = tid; i < 8*768; i += 256){
    int c2 = i >> 9;               // i/512? no: 768 per concept
    c2 = i / 768; int h = i - c2*768;
    sh[c2][h] = ce[(size_t)(cg*8+c2)*768 + h];
  }
  __syncthreads();
  float aK0=0.f, aV0=0.f, aK1=0.f, aV1=0.f;
  #pragma unroll 4
  for (int h=0; h<768; ++h){
    float wk = Wk[(size_t)h*768 + j];
    float wv = Wv[(size_t)h*768 + j];
    float x0 = sh[cl*2][h], x1 = sh[cl*2+1][h];
    aK0 += x0*wk; aV0 += x0*wv;
    aK1 += x1*wk; aV1 += x1*wv;
  }
  float bkj = bk[j], bvj = bv[j];
  int c0 = cg*8 + cl*2;
  Kc[(size_t)c0*768 + j]     = f2bf(aK0 + bkj);
  Kc[(size_t)(c0+1)*768 + j] = f2bf(aK1 + bkj);
  VT[(size_t)j*64 + c0]      = f2bf(aV0 + bvj);
  VT[(size_t)j*64 + c0+1]    = f2bf(aV1 + bvj);
}

// 15 blocks: 0-11 wg1c (64 cols each, 4-way k-split); 12-14 cp
__global__ void prep_misc(const float* __restrict__ Wg1, const float* __restrict__ ce,
                          float* __restrict__ wg1c, float* __restrict__ cp){
  __shared__ float red[4][64];
  int b = blockIdx.x, tid = threadIdx.x;
  if (b < 12){
    int j = b*64 + (tid & 63);
    int kq = tid >> 6;
    float s = 0.f;
    for (int r=0; r<192; ++r)
      s += Wg1[(size_t)(1536 + kq*192 + r)*768 + j];
    red[kq][tid&63] = s;
    __syncthreads();
    if (tid < 64) wg1c[b*64+tid] = red[0][tid]+red[1][tid]+red[2][tid]+red[3][tid];
  } else {
    int h = (b-12)*256 + tid;
    float s = 0.f;
    #pragma unroll
    for (int c2=0; c2<64; ++c2) s += ce[(size_t)c2*768 + h];
    cp[h] = s * (1.f/64.f);
  }
}

// hs f32 -> bf16 pre-swizzled hole1 + partial column sums (fused old pool1). 512 blocks x 384 thr.
__global__ __launch_bounds__(384) void prep_hs(const float* __restrict__ hs,
                                               float* __restrict__ outp, float* __restrict__ tpp){
  __shared__ float csum[4][768];
  int tid = threadIdx.x;
  int c = tid % 96, rg = tid / 96;          // 96 chunk-cols x 4 row-groups
  size_t r0 = (size_t)blockIdx.x * 128;
  u16* holes = (u16*)outp;
  float s[8];
  #pragma unroll
  for (int j=0;j<8;++j) s[j]=0.f;
  #pragma unroll 4
  for (int i=0; i<32; ++i){
    size_t row = r0 + rg*32 + i;
    const float* p = hs + row*768 + c*8;
    f32x4 x = __builtin_nontemporal_load((const f32x4*)p);
    f32x4 y = __builtin_nontemporal_load((const f32x4*)(p+4));
    *(bf16x8*)&holes[row*1536 + pch(c,(int)row)*8] = pack8(x,y);
    #pragma unroll
    for (int j=0;j<4;++j){ s[j]+=x[j]; s[4+j]+=y[j]; }
  }
  #pragma unroll
  for (int j=0;j<8;++j) csum[rg][c*8+j] = s[j];
  __syncthreads();
  for (int cc=tid; cc<768; cc+=384)
    tpp[(size_t)blockIdx.x*768 + cc] = csum[0][cc]+csum[1][cc]+csum[2][cc]+csum[3][cc];
}

__global__ void pool2(const float* __restrict__ tpp, float* __restrict__ tp){
  int b = blockIdx.x / 3, hc = blockIdx.x % 3;
  int h = hc*256 + threadIdx.x;
  float s = 0.f;
  #pragma unroll
  for (int k=0; k<32; ++k) s += tpp[((size_t)b*32 + k)*768 + h];
  tp[(size_t)b*768 + h] = s * (1.f/4096.f);
}
__global__ void pool3(const float* __restrict__ tp, const float* __restrict__ cp, float* __restrict__ rel){
  int b = blockIdx.x;
  float a=0.f, n1=0.f, n2=0.f;
  for (int h = threadIdx.x; h < 768; h += 256){
    float t = tp[(size_t)b*768 + h], c = cp[h];
    a += t*c; n1 += t*t; n2 += c*c;
  }
  #pragma unroll
  for (int m=1; m<64; m<<=1){ a+=__shfl_xor(a,m); n1+=__shfl_xor(n1,m); n2+=__shfl_xor(n2,m); }
  __shared__ float r3[3][4];
  int w = threadIdx.x >> 6;
  if ((threadIdx.x & 63) == 0){ r3[0][w]=a; r3[1][w]=n1; r3[2][w]=n2; }
  __syncthreads();
  if (threadIdx.x == 0){
    float A = r3[0][0]+r3[0][1]+r3[0][2]+r3[0][3];
    float N1= r3[1][0]+r3[1][1]+r3[1][2]+r3[1][3];
    float N2= r3[2][0]+r3[2][1]+r3[2][2]+r3[2][3];
    rel[b] = A / (fmaxf(sqrtf(N1),1e-8f) * fmaxf(sqrtf(N2),1e-8f));
  }
}

// ---------------- gq: Q = scale*(hs @ Wq + bq) -> hole2 (XCD-grouped grid) ----------------
__global__ __launch_bounds__(256) void gq(const short* __restrict__ WqI,
                                          const float* __restrict__ bq, float* outp){
  __shared__ short A0[8192], A1[8192], B0[8192], B1[8192];
  const int tid = threadIdx.x, lane = tid & 63, w = tid >> 6;
  const int l15 = lane & 15, g = lane >> 4;
  const int bid = blockIdx.x;
  const int nb = (bid >> 3) % 6, mt = (bid/48)*8 + (bid & 7);
  const int wm = w & 1, wn = w >> 1;
  const size_t t0 = (size_t)mt*128;
  u16* holes = (u16*)outp;
  const u16* Arow = holes + t0*1536;
  const short* Wimg = WqI + (size_t)nb*6*16384;
  f32x4 acc[4][4];
  #pragma unroll
  for (int i=0;i<4;++i)
    #pragma unroll
    for (int j=0;j<4;++j) acc[i][j] = (f32x4){0.f,0.f,0.f,0.f};
  stA128(A0, Arow, 0, w, lane);
  stWB(B0, Wimg, 0, w, lane);
  __syncthreads();
  #pragma unroll
  for (int ks2=0; ks2<12; ++ks2){
    const short* Ac = (ks2&1)? A1 : A0;
    const short* Bc = (ks2&1)? B1 : B0;
    short* An = (ks2&1)? A0 : A1;
    short* Bn = (ks2&1)? B0 : B1;
    if (ks2<11){
      stA128(An, Arow, ks2+1, w, lane);
      stWB(Bn, Wimg + (size_t)(((ks2+1)>>1))*16384, (ks2+1)&1, w, lane);
    }
    #pragma unroll
    for (int ks=0; ks<2; ++ks){
      bf16x8 a[4], b[4];
      #pragma unroll
      for (int mf=0; mf<4; ++mf){ int r = wm*64+mf*16+l15; a[mf] = *(const bf16x8*)&Ac[r*64 + (((ks*4+g)^(r&7))<<3)]; }
      #pragma unroll
      for (int nf=0; nf<4; ++nf){ int r = wn*64+nf*16+l15; b[nf] = *(const bf16x8*)&Bc[r*64 + (((ks*4+g)^(r&7))<<3)]; }
      #pragma unroll
      for (int mf=0; mf<4; ++mf)
        #pragma unroll
        for (int nf=0; nf<4; ++nf)
          acc[mf][nf] = MFMA(a[mf], b[nf], acc[mf][nf]);
    }
    __syncthreads();
  }
  #pragma unroll
  for (int mf=0; mf<4; ++mf)
    #pragma unroll
    for (int nf=0; nf<4; ++nf)
      #pragma unroll
      for (int r=0; r<4; ++r){
        int grow = wm*64 + mf*16 + g*4 + r;
        int col = nb*128 + wn*64 + nf*16 + l15;
        float v = (acc[mf][nf][r] + bq[col]) * 0.10206207262f;
        holes[(t0+grow)*1536 + 768 + pch(col>>3, grow)*8 + (col&7)] = (u16)f2bf(v);
      }
}

// ---------------- att: attention from Q(hole2) -> ctx(hole2) + attn_avg ----------------
__global__ __launch_bounds__(256) void att(const short* __restrict__ Kc,
                                           const short* __restrict__ VT, float* outp){
  __shared__ short attb[4096];   // [64][64] swz
  const int tid = threadIdx.x, lane = tid & 63, w = tid >> 6;
  const int l15 = lane & 15, g = lane >> 4;
  const size_t t0 = (size_t)blockIdx.x * 64;
  const int arow = w*16 + l15;
  const int drow = w*16 + g*4;
  u16* holes = (u16*)outp;
  float aavg[16];
  #pragma unroll
  for (int i=0;i<16;++i) aavg[i]=0.f;

  #pragma unroll 1
  for (int h=0; h<8; ++h){
    f32x4 sa[4];
    #pragma unroll
    for (int i=0;i<4;++i) sa[i]=(f32x4){0.f,0.f,0.f,0.f};
    #pragma unroll
    for (int ks=0; ks<3; ++ks){
      int kc = 12*h + ks*4 + g;
      bf16x8 a = *(const bf16x8*)&holes[(t0+arow)*1536 + 768 + pch(kc, arow)*8];
      #pragma unroll
      for (int cf2=0; cf2<4; ++cf2)
        sa[cf2] = MFMA(a, *(const bf16x8*)&Kc[(size_t)(cf2*16+l15)*768 + h*96 + ks*32 + g*8], sa[cf2]);
    }
    #pragma unroll
    for (int r=0; r<4; ++r){
      float v0=sa[0][r], v1=sa[1][r], v2=sa[2][r], v3=sa[3][r];
      float m = fmaxf(fmaxf(v0,v1),fmaxf(v2,v3));
      m = fmaxf(m,__shfl_xor(m,1)); m = fmaxf(m,__shfl_xor(m,2));
      m = fmaxf(m,__shfl_xor(m,4)); m = fmaxf(m,__shfl_xor(m,8));
      float e0=__expf(v0-m),e1=__expf(v1-m),e2=__expf(v2-m),e3=__expf(v3-m);
      float s=e0+e1+e2+e3;
      s+=__shfl_xor(s,1); s+=__shfl_xor(s,2); s+=__shfl_xor(s,4); s+=__shfl_xor(s,8);
      float inv = 1.f/s;
      e0*=inv; e1*=inv; e2*=inv; e3*=inv;
      attb[swz(drow+r,  0+l15, 64)] = f2bf(e0);
      attb[swz(drow+r, 16+l15, 64)] = f2bf(e1);
      attb[swz(drow+r, 32+l15, 64)] = f2bf(e2);
      attb[swz(drow+r, 48+l15, 64)] = f2bf(e3);
      aavg[0+r]+=e0*0.125f; aavg[4+r]+=e1*0.125f; aavg[8+r]+=e2*0.125f; aavg[12+r]+=e3*0.125f;
    }
    // PV -> ctx bf16 (overwrites this head's Q cols; reads of them are done)
    {
      f32x4 pv[6];
      #pragma unroll
      for (int i=0;i<6;++i) pv[i]=(f32x4){0.f,0.f,0.f,0.f};
      #pragma unroll
      for (int ks=0; ks<2; ++ks){
        bf16x8 a = *(const bf16x8*)&attb[swz(arow, ks*32+g*8, 64)];
        #pragma unroll
        for (int nt=0; nt<6; ++nt)
          pv[nt] = MFMA(a, *(const bf16x8*)&VT[(size_t)(h*96 + nt*16 + l15)*64 + ks*32 + g*8], pv[nt]);
      }
      #pragma unroll
      for (int nt=0; nt<6; ++nt)
        #pragma unroll
        for (int r=0; r<4; ++r){
          int row = drow + r;
          int col = h*96 + nt*16 + l15;
          holes[(t0+row)*1536 + 768 + pch(col>>3, row)*8 + (col&7)] = (u16)f2bf(pv[nt][r]);
        }
    }
  }
  #pragma unroll
  for (int cf2=0; cf2<4; ++cf2)
    #pragma unroll
    for (int r=0; r<4; ++r)
      __builtin_nontemporal_store(aavg[cf2*4+r],
          &outp[(size_t)50331648 + (t0 + drow + r)*64 + cf2*16 + l15]);
}

// ---------------- gwo: ctxo = ctx @ Wo + bo -> hole2 (ctx held in regs first) ----------------
__global__ __launch_bounds__(256) void gwo(const short* __restrict__ WoI,
                                           const float* __restrict__ bo, float* outp){
  __shared__ short B0[8192], B1[8192];
  const int tid = threadIdx.x, lane = tid & 63, w = tid >> 6;
  const int l15 = lane & 15, g = lane >> 4;
  const size_t t0 = (size_t)blockIdx.x * 64;
  const int arow = w*16 + l15;
  const int drow = w*16 + g*4;
  u16* holes = (u16*)outp;
  bf16x8 af[24];
  #pragma unroll
  for (int kk=0; kk<24; ++kk){
    int kc = kk*4 + g;
    af[kk] = *(const bf16x8*)&holes[(t0+arow)*1536 + 768 + pch(kc, arow)*8];
  }
  stWB(B0, WoI, 0, w, lane);
  __syncthreads();
  #pragma unroll 1
  for (int nb=0; nb<6; ++nb){
    f32x4 acc[8];
    #pragma unroll
    for (int i=0;i<8;++i) acc[i]=(f32x4){0.f,0.f,0.f,0.f};
    #pragma unroll
    for (int ks2=0; ks2<12; ++ks2){
      const short* Bc = (ks2&1)? B1 : B0;
      short* Bn = (ks2&1)? B0 : B1;
      if (ks2<11)      stWB(Bn, WoI + (size_t)(nb*6 + ((ks2+1)>>1))*16384, (ks2+1)&1, w, lane);
      else if (nb<5)   stWB(Bn, WoI + (size_t)((nb+1)*6)*16384, 0, w, lane);
      #pragma unroll
      for (int ks=0; ks<2; ++ks){
        bf16x8 a = af[ks2*2 + ks];
        #pragma unroll
        for (int nf=0; nf<8; ++nf){
          int br = nf*16 + l15;
          bf16x8 b = *(const bf16x8*)&Bc[br*64 + (((ks*4+g)^(br&7))<<3)];
          acc[nf] = MFMA(a, b, acc[nf]);
        }
      }
      __syncthreads();
    }
    #pragma unroll
    for (int nf=0; nf<8; ++nf)
      #pragma unroll
      for (int r=0; r<4; ++r){
        int row = drow + r;
        int col = nb*128 + nf*16 + l15;
        float v = acc[nf][r] + bo[col];
        holes[(t0+row)*1536 + 768 + pch(col>>3, row)*8 + (col&7)] = (u16)f2bf(v);
      }
  }
}

// ---------------- gate_mm: per-(mt,nb) block, K=1536 (both passes), partial relu-dot -> gpart ----------------
__global__ __launch_bounds__(256) void gate_mm(const short* __restrict__ WaI,
    const short* __restrict__ WbI, const float* __restrict__ bg1,
    const float* __restrict__ wg1c, const float* __restrict__ Wg2,
    const float* __restrict__ rel, float* __restrict__ gpart, float* outp){
  __shared__ short A0[8192], A1[8192], B0[8192], B1[8192];
  const int tid = threadIdx.x, lane = tid & 63, w = tid >> 6;
  const int l15 = lane & 15, g = lane >> 4;
  const int bid = blockIdx.x;
  const int nb = (bid >> 3) % 6, mt = (bid/48)*8 + (bid & 7);
  const int wm = w & 1, wn = w >> 1;
  const size_t t0 = (size_t)mt*128;
  const float relb = rel[t0 >> 12];
  u16* holes = (u16*)outp;
  const u16* h1p = holes + t0*1536;        // hs bf16
  const u16* h2p = h1p + 768;              // ctxo bf16
  f32x4 acc[4][4];
  #pragma unroll
  for (int i=0;i<4;++i)
    #pragma unroll
    for (int j=0;j<4;++j) acc[i][j]=(f32x4){0.f,0.f,0.f,0.f};
  stA128(A0, h1p, 0, w, lane);
  stWB(B0, WaI + (size_t)nb*6*16384, 0, w, lane);
  __syncthreads();
  #pragma unroll
  for (int pass=0; pass<2; ++pass){
    const short* Wimg = (pass? WbI : WaI) + (size_t)nb*6*16384;
    const u16* Ap = pass ? h2p : h1p;
    #pragma unroll
    for (int ks2=0; ks2<12; ++ks2){
      const short* Ac = (ks2&1)? A1 : A0;
      const short* Bc = (ks2&1)? B1 : B0;
      short* An = (ks2&1)? A0 : A1;
      short* Bn = (ks2&1)? B0 : B1;
      if (ks2<11){
        stA128(An, Ap, ks2+1, w, lane);
        stWB(Bn, Wimg + (size_t)(((ks2+1)>>1))*16384, (ks2+1)&1, w, lane);
      } else if (pass==0){
        stA128(An, h2p, 0, w, lane);
        stWB(Bn, WbI + (size_t)nb*6*16384, 0, w, lane);
      }
      #pragma unroll
      for (int ks=0; ks<2; ++ks){
        bf16x8 a[4], b[4];
        #pragma unroll
        for (int mf=0; mf<4; ++mf){ int r = wm*64+mf*16+l15; a[mf] = *(const bf16x8*)&Ac[r*64 + (((ks*4+g)^(r&7))<<3)]; }
        #pragma unroll
        for (int nf=0; nf<4; ++nf){ int r = wn*64+nf*16+l15; b[nf] = *(const bf16x8*)&Bc[r*64 + (((ks*4+g)^(r&7))<<3)]; }
        #pragma unroll
        for (int mf=0; mf<4; ++mf)
          #pragma unroll
          for (int nf=0; nf<4; ++nf)
            acc[mf][nf] = MFMA(a[mf], b[nf], acc[mf][nf]);
      }
      __syncthreads();
    }
  }
  float gp[4][4];
  #pragma unroll
  for (int mf=0; mf<4; ++mf)
    #pragma unroll
    for (int r=0; r<4; ++r) gp[mf][r]=0.f;
  #pragma unroll
  for (int mf=0; mf<4; ++mf)
    #pragma unroll
    for (int nf=0; nf<4; ++nf)
      #pragma unroll
      for (int r=0; r<4; ++r){
        int col = nb*128 + wn*64 + nf*16 + l15;
        gp[mf][r] += fmaxf(acc[mf][nf][r] + bg1[col] + relb*wg1c[col], 0.f) * Wg2[col];
      }
  #pragma unroll
  for (int mf=0; mf<4; ++mf)
    #pragma unroll
    for (int r=0; r<4; ++r){
      float v = gp[mf][r];
      v += __shfl_xor(v,1); v += __shfl_xor(v,2); v += __shfl_xor(v,4); v += __shfl_xor(v,8);
      gp[mf][r] = v;
    }
  __syncthreads();
  float* gred = (float*)B0;
  if (l15 == 0)
    #pragma unroll
    for (int mf=0; mf<4; ++mf)
      #pragma unroll
      for (int r=0; r<4; ++r)
        gred[wn*128 + wm*64 + mf*16 + g*4 + r] = gp[mf][r];
  __syncthreads();
  if (tid < 128)
    gpart[(size_t)nb*65536 + t0 + tid] = gred[tid] + gred[128+tid];
}

// ---------------- lnk: out = LN(hs + sigmoid(sum gpart + bg2)*ctxo) ----------------
__global__ __launch_bounds__(256) void lnk(const float* __restrict__ gpart,
    const float* __restrict__ bg2, const float* __restrict__ lng,
    const float* __restrict__ lnb, float* outp){
  const int tid = threadIdx.x, lane = tid & 63, w = tid >> 6;
  u16* holes = (u16*)outp;
  const float bg2v = bg2[0];
  #pragma unroll 1
  for (int i=0; i<8; ++i){
    int row = blockIdx.x*32 + w*8 + i;
    float gsum = bg2v;
    #pragma unroll
    for (int nb2=0; nb2<6; ++nb2) gsum += gpart[(size_t)nb2*65536 + row];
    float gg = 1.f/(1.f + __expf(-gsum));
    int c1 = lane, c2 = 64 + (lane & 31);
    size_t rb = (size_t)row*1536;
    bf16x8 hv1 = *(const bf16x8*)&holes[rb + pch(c1,row)*8];
    bf16x8 ov1 = *(const bf16x8*)&holes[rb + 768 + pch(c1,row)*8];
    bf16x8 hv2 = *(const bf16x8*)&holes[rb + pch(c2,row)*8];
    bf16x8 ov2 = *(const bf16x8*)&holes[rb + 768 + pch(c2,row)*8];
    float x1[8], x2[8];
    float sum=0.f, sq=0.f;
    #pragma unroll
    for (int j=0;j<8;++j){ float x = bf2f(hv1[j]) + gg*bf2f(ov1[j]); x1[j]=x; sum+=x; sq+=x*x; }
    if (lane < 32){
      #pragma unroll
      for (int j=0;j<8;++j){ float x = bf2f(hv2[j]) + gg*bf2f(ov2[j]); x2[j]=x; sum+=x; sq+=x*x; }
    }
    #pragma unroll
    for (int m=1; m<64; m<<=1){ sum += __shfl_xor(sum,m); sq += __shfl_xor(sq,m); }
    float mu = sum * (1.f/768.f);
    float var = sq * (1.f/768.f) - mu*mu;
    float rs = rsqrtf(var + 1e-5f);
    {
      f32x4 ga = *(const f32x4*)&lng[c1*8], gb = *(const f32x4*)&lng[c1*8+4];
      f32x4 ba = *(const f32x4*)&lnb[c1*8], bb = *(const f32x4*)&lnb[c1*8+4];
      f32x4 o0, o1;
      #pragma unroll
      for (int j=0;j<4;++j){ o0[j] = (x1[j]-mu)*rs*ga[j]+ba[j]; o1[j] = (x1[4+j]-mu)*rs*gb[j]+bb[j]; }
      *(f32x4*)&outp[(size_t)row*768 + c1*8] = o0;
      *(f32x4*)&outp[(size_t)row*768 + c1*8 + 4] = o1;
    }
    if (lane < 32){
      f32x4 ga = *(const f32x4*)&lng[c2*8], gb = *(const f32x4*)&lng[c2*8+4];
      f32x4 ba = *(const f32x4*)&lnb[c2*8], bb = *(const f32x4*)&lnb[c2*8+4];
      f32x4 o0, o1;
      #pragma unroll
      for (int j=0;j<4;++j){ o0[j] = (x2[j]-mu)*rs*ga[j]+ba[j]; o1[j] = (x2[4+j]-mu)*rs*gb[j]+bb[j]; }
      *(f32x4*)&outp[(size_t)row*768 + c2*8] = o0;
      *(f32x4*)&outp[(size_t)row*768 + c2*8 + 4] = o1;
    }
  }
}

extern "C" void kernel_launch(void* const* d_in, const int* in_sizes, int n_in,
                              void* d_out, int out_size, void* d_ws, size_t ws_size,
                              hipStream_t stream) {
  (void)in_sizes; (void)n_in; (void)out_size; (void)ws_size;
  const float* hs  = (const float*)d_in[0];
  const float* ce  = (const float*)d_in[1];
  const float* Wq  = (const float*)d_in[2];
  const float* bq  = (const float*)d_in[3];
  const float* Wk  = (const float*)d_in[4];
  const float* bk  = (const float*)d_in[5];
  const float* Wv  = (const float*)d_in[6];
  const float* bv  = (const float*)d_in[7];
  const float* Wo  = (const float*)d_in[8];
  const float* bo  = (const float*)d_in[9];
  const float* Wg1 = (const float*)d_in[10];
  const float* bg1 = (const float*)d_in[11];
  const float* Wg2 = (const float*)d_in[12];
  const float* bg2 = (const float*)d_in[13];
  const float* lng = (const float*)d_in[14];
  const float* lnb = (const float*)d_in[15];
  char* ws = (char*)d_ws;
  short* WqI   = (short*)(ws + 0);
  short* WoI   = (short*)(ws + 1179648);
  short* WaI   = (short*)(ws + 2359296);
  short* WbI   = (short*)(ws + 3538944);
  short* Kc    = (short*)(ws + 4718592);
  short* VT    = (short*)(ws + 4816896);
  float* wg1c  = (float*)(ws + 4915200);
  float* cp    = (float*)(ws + 4918272);
  float* tp    = (float*)(ws + 4921344);
  float* rel   = (float*)(ws + 4970496);
  float* tpp   = (float*)(ws + 4970752);   // 512*768*4 = 1572864
  float* gpart = (float*)(ws + 4970752);   // aliases tpp (dead by gate_mm time); 6*65536*4
  float* outp  = (float*)d_out;

  prep_w   <<<144, 256, 0, stream>>>(Wq, Wo, Wg1, WqI, WoI, WaI, WbI);
  prep_kv  <<<96,  256, 0, stream>>>(ce, Wk, bk, Wv, bv, Kc, VT);
  prep_misc<<<15,  256, 0, stream>>>(Wg1, ce, wg1c, cp);
  prep_hs  <<<512, 384, 0, stream>>>(hs, outp, tpp);
  pool2    <<<48,  256, 0, stream>>>(tpp, tp);
  pool3    <<<16,  256, 0, stream>>>(tp, cp, rel);
  gq       <<<3072,256, 0, stream>>>(WqI, bq, outp);
  att      <<<1024,256, 0, stream>>>(Kc, VT, outp);
  gwo      <<<1024,256, 0, stream>>>(WoI, bo, outp);
  gate_mm  <<<3072,256, 0, stream>>>(WaI, WbI, bg1, wg1c, Wg2, rel, gpart, outp);
  lnk      <<<2048,256, 0, stream>>>(gpart, bg2, lng, lnb, outp);
}